// Round 1
// baseline (160.539 us; speedup 1.0000x reference)
//
#include <hip/hip_runtime.h>
#include <stdint.h>

// CrossAttentionLayer: B=2, Q=256, N=16384, C=256, H=8, d=32
#define B_ 2
#define Q_ 256
#define N_ 16384
#define C_ 256
#define H_ 8
#define D_ 32
#define NC_ 32                      // attention split-N chunks (N/NC = 512 per block)
#define SCALE 0.17677669529663687f  // 1/sqrt(32)

typedef __bf16 bf16x8 __attribute__((ext_vector_type(8)));
typedef float f32x4 __attribute__((ext_vector_type(4)));

__device__ __forceinline__ uint16_t f2bf(float f) {
  union { float f; uint32_t u; } c; c.f = f;
  uint32_t r = c.u + 0x7FFFu + ((c.u >> 16) & 1u);  // RNE
  return (uint16_t)(r >> 16);
}

// ---------------------------------------------------------------------------
// Kernel 1: pack vid_mask (B,Q,N) fp32 -> bitmask (B,Q,N/32), bit=1 => blocked.
// Applies the all-blocked fallback (row fully blocked -> clear all bits).
// ---------------------------------------------------------------------------
__global__ __launch_bounds__(256) void pack_mask(const float* __restrict__ vm,
                                                 uint32_t* __restrict__ mb) {
  const int bq = blockIdx.x;
  const float* row = vm + (size_t)bq * N_;
  __shared__ uint32_t words[N_ / 32];
  __shared__ int wcnt[4];
  __shared__ int tot;
  const int t = threadIdx.x;
  const int lane = t & 63;
  int cnt = 0;
  for (int i = 0; i < N_ / 256; ++i) {
    const int n = i * 256 + t;
    const bool blocked = row[n] < 0.5f;
    cnt += blocked ? 1 : 0;
    const unsigned long long bal = __ballot(blocked);
    if (lane == 0) {
      const int w0 = n >> 5;  // n is 64-aligned for lane 0
      words[w0] = (uint32_t)bal;
      words[w0 + 1] = (uint32_t)(bal >> 32);
    }
  }
  for (int o = 32; o > 0; o >>= 1) cnt += __shfl_down(cnt, o, 64);
  if (lane == 0) wcnt[t >> 6] = cnt;
  __syncthreads();
  if (t == 0) tot = wcnt[0] + wcnt[1] + wcnt[2] + wcnt[3];
  __syncthreads();
  const bool allb = (tot == N_);
  uint32_t* dst = mb + (size_t)bq * (N_ / 32);
  for (int i = t; i < N_ / 32; i += 256) dst[i] = allb ? 0u : words[i];
}

// ---------------------------------------------------------------------------
// Kernel 2: Q projection. q = ((queries+query_embed) @ wq^T + bq) * SCALE,
// stored bf16 as (B,H,Q,32). One block per (b,q) row.
// ---------------------------------------------------------------------------
__global__ __launch_bounds__(256) void qproj(const float* __restrict__ queries,
                                             const float* __restrict__ query_embed,
                                             const float* __restrict__ w,
                                             const float* __restrict__ bias,
                                             uint16_t* __restrict__ Qb) {
  const int bq = blockIdx.x;
  const int b = bq >> 8, q = bq & 255;
  __shared__ float x[C_];
  const int t = threadIdx.x;
  x[t] = queries[(size_t)bq * C_ + t] + query_embed[(size_t)bq * C_ + t];
  __syncthreads();
  const float* wr = w + (size_t)t * C_;  // wq row t (rows 0..255 of in_proj_w)
  float acc = bias[t];
#pragma unroll 8
  for (int j = 0; j < C_; ++j) acc = fmaf(x[j], wr[j], acc);
  acc *= SCALE;
  const int h = t >> 5, dk = t & 31;
  Qb[((size_t)(b * H_ + h) * Q_ + q) * D_ + dk] = f2bf(acc);
}

// ---------------------------------------------------------------------------
// Kernel 3: K/V projection (the big GEMM).
//   K' = wk @ (vf+pe) + bk   -> stored (B,N,C) bf16 (LDS-transposed on output)
//   V' = wv @ vf + bv        -> stored (B,C,N) bf16 (direct store)
// Block: 512 thr = 8 waves, tile 128 cout x 128 n, K-loop over cin in 32s.
// A (weights) and B (activations) fragments loaded directly from global fp32.
// ---------------------------------------------------------------------------
__global__ __launch_bounds__(512) void kvproj(const float* __restrict__ vf,
                                              const float* __restrict__ pe,
                                              const float* __restrict__ w,
                                              const float* __restrict__ bias,
                                              uint16_t* __restrict__ Kb,
                                              uint16_t* __restrict__ Vb) {
  const int bid = blockIdx.x;
  const int nb = bid & 127, cb = (bid >> 7) & 1, b = bid >> 8;
  const int n0 = nb * 128, c0 = cb * 128;
  const int t = threadIdx.x, wid = t >> 6, lane = t & 63;
  const int g = lane >> 4, c15 = lane & 15;
  const int wc = wid >> 2, wn = wid & 3;  // cout-64 group, n-32 group
  const float* X = vf + (size_t)b * C_ * N_;  // [cin][n]
  const float* P = pe + (size_t)b * C_ * N_;
  const float* WK = w + 256 * C_;
  const float* WV = w + 512 * C_;

  f32x4 ak[4][2], av[4][2];
#pragma unroll
  for (int cf = 0; cf < 4; ++cf) {
    const int cbase = c0 + wc * 64 + cf * 16 + 4 * g;
    f32x4 ik, iv;
#pragma unroll
    for (int j = 0; j < 4; ++j) {
      ik[j] = bias[256 + cbase + j];
      iv[j] = bias[512 + cbase + j];
    }
    ak[cf][0] = ik; ak[cf][1] = ik;
    av[cf][0] = iv; av[cf][1] = iv;
  }

  for (int cc = 0; cc < C_; cc += 32) {
    bf16x8 AK[4], AV[4];
#pragma unroll
    for (int cf = 0; cf < 4; ++cf) {
      const int row = c0 + wc * 64 + cf * 16 + c15;
      const float* kr = WK + (size_t)row * C_ + cc + g * 8;
      const float* vr = WV + (size_t)row * C_ + cc + g * 8;
#pragma unroll
      for (int r = 0; r < 8; ++r) {
        AK[cf][r] = (__bf16)kr[r];
        AV[cf][r] = (__bf16)vr[r];
      }
    }
#pragma unroll
    for (int nf = 0; nf < 2; ++nf) {
      const int ncol = n0 + wn * 32 + nf * 16 + c15;
      const float* xp = X + (size_t)(cc + g * 8) * N_ + ncol;
      const float* pp = P + (size_t)(cc + g * 8) * N_ + ncol;
      bf16x8 BK, BV;
#pragma unroll
      for (int r = 0; r < 8; ++r) {
        const float xv = xp[(size_t)r * N_];
        const float pv = pp[(size_t)r * N_];
        BV[r] = (__bf16)xv;
        BK[r] = (__bf16)(xv + pv);
      }
#pragma unroll
      for (int cf = 0; cf < 4; ++cf) {
        ak[cf][nf] = __builtin_amdgcn_mfma_f32_16x16x32_bf16(AK[cf], BK, ak[cf][nf], 0, 0, 0);
        av[cf][nf] = __builtin_amdgcn_mfma_f32_16x16x32_bf16(AV[cf], BV, av[cf][nf], 0, 0, 0);
      }
    }
  }

  // V: direct store into (B, C, N). C/D frag: col(l&15)=n, row(4g+j)=cout.
  uint16_t* Vp = Vb + (size_t)b * C_ * N_;
#pragma unroll
  for (int cf = 0; cf < 4; ++cf)
#pragma unroll
    for (int nf = 0; nf < 2; ++nf)
#pragma unroll
      for (int j = 0; j < 4; ++j) {
        const int cout = c0 + wc * 64 + cf * 16 + 4 * g + j;
        const int n = n0 + wn * 32 + nf * 16 + c15;
        Vp[(size_t)cout * N_ + n] = f2bf(av[cf][nf][j]);
      }

  // K: transpose via LDS, then coalesced rows into (B, N, C).
  __shared__ __align__(16) uint16_t klds[128][136];  // [n-local][cout-local], padded
#pragma unroll
  for (int cf = 0; cf < 4; ++cf)
#pragma unroll
    for (int nf = 0; nf < 2; ++nf)
#pragma unroll
      for (int j = 0; j < 4; ++j) {
        const int cl = wc * 64 + cf * 16 + 4 * g + j;
        const int nl = wn * 32 + nf * 16 + c15;
        klds[nl][cl] = f2bf(ak[cf][nf][j]);
      }
  __syncthreads();
  uint16_t* Kp = Kb + (size_t)b * N_ * C_;
#pragma unroll
  for (int it = 0; it < 4; ++it) {
    const int idx = it * 512 + t;  // 128 rows x 16 chunks of 16B
    const int nl = idx >> 4, ch = idx & 15;
    const uint4 vdat = *reinterpret_cast<const uint4*>(&klds[nl][ch * 8]);
    *reinterpret_cast<uint4*>(&Kp[(size_t)(n0 + nl) * C_ + c0 + ch * 8]) = vdat;
  }
}

// ---------------------------------------------------------------------------
// Kernel 4: attention over an N-chunk of 512 keys, all 256 queries of one
// (b, h). No max-tracking: P = exp(S) (masked -> 0), partials = unnormalized
// sum of P*V plus sum of P. Block: 512 thr = 8 waves, wave owns 32 q rows.
// ---------------------------------------------------------------------------
__global__ __launch_bounds__(512) void attn(const uint16_t* __restrict__ Qb,
                                            const uint16_t* __restrict__ Kb,
                                            const uint16_t* __restrict__ Vb,
                                            const uint32_t* __restrict__ mb,
                                            float* __restrict__ ctx_part,
                                            float* __restrict__ lsum_part) {
  const int bid = blockIdx.x;
  const int nc = bid & 31, h = (bid >> 5) & 7, b = bid >> 8;
  const int t = threadIdx.x, wid = t >> 6, lane = t & 63;
  const int g = lane >> 4, c15 = lane & 15;
  const int qw0 = wid * 32;
  const int nbase = nc * (N_ / NC_);  // 512-wide chunk

  __shared__ __align__(16) uint16_t kst[128][40];       // [n-local][dk], pad->80B rows
  __shared__ __align__(16) uint16_t vst[32][136];       // [dv][n-local 128], pad->272B
  __shared__ __align__(16) uint16_t plds[8][32][40];    // per-wave P tile

  const uint16_t* Qp = Qb + (size_t)(b * H_ + h) * Q_ * D_;
  bf16x8 qfr[2];
#pragma unroll
  for (int qf = 0; qf < 2; ++qf)
    qfr[qf] = *reinterpret_cast<const bf16x8*>(Qp + (size_t)(qw0 + qf * 16 + c15) * D_ + g * 8);

  f32x4 acc[2][2];
  const f32x4 zero4 = {0.f, 0.f, 0.f, 0.f};
#pragma unroll
  for (int qf = 0; qf < 2; ++qf)
#pragma unroll
    for (int dvf = 0; dvf < 2; ++dvf) acc[qf][dvf] = zero4;
  float lsum[2][4] = {};

  const uint32_t* mrow = mb + (size_t)b * Q_ * (N_ / 32);

  for (int ss = 0; ss < (N_ / NC_) / 128; ++ss) {  // 4 stage-steps of 128 n
    const int nstart = nbase + ss * 128;
    {  // stage K tile: 128 rows x 32 dk
      const int row = t >> 2, ch = t & 3;
      const uint4 vdat = *reinterpret_cast<const uint4*>(
          Kb + ((size_t)(b * N_ + nstart + row)) * C_ + h * D_ + ch * 8);
      *reinterpret_cast<uint4*>(&kst[row][ch * 8]) = vdat;
    }
    {  // stage V tile: 32 dv rows x 128 n
      const int row = t >> 4, ch = t & 15;
      const uint4 vdat = *reinterpret_cast<const uint4*>(
          Vb + ((size_t)(b * C_ + h * D_ + row)) * N_ + nstart + ch * 8);
      *reinterpret_cast<uint4*>(&vst[row][ch * 8]) = vdat;
    }
    __syncthreads();

#pragma unroll
    for (int sub = 0; sub < 4; ++sub) {  // 32 n per sub-step
      const int nl0 = sub * 32;
      bf16x8 kfr[2];
#pragma unroll
      for (int nf = 0; nf < 2; ++nf)
        kfr[nf] = *reinterpret_cast<const bf16x8*>(&kst[nl0 + nf * 16 + c15][g * 8]);
      f32x4 s[2][2];
#pragma unroll
      for (int qf = 0; qf < 2; ++qf)
#pragma unroll
        for (int nf = 0; nf < 2; ++nf)
          s[qf][nf] = __builtin_amdgcn_mfma_f32_16x16x32_bf16(qfr[qf], kfr[nf], zero4, 0, 0, 0);

      const int wofs = (nstart + nl0) >> 5;  // one 32-bit word covers this sub-step
#pragma unroll
      for (int qf = 0; qf < 2; ++qf) {
#pragma unroll
        for (int j = 0; j < 4; ++j) {
          const int q = qw0 + qf * 16 + 4 * g + j;
          const uint32_t wmask = mrow[(size_t)q * (N_ / 32) + wofs];
#pragma unroll
          for (int nf = 0; nf < 2; ++nf) {
            const int bit = nf * 16 + c15;
            const float p = ((wmask >> bit) & 1u) ? 0.0f : __expf(s[qf][nf][j]);
            lsum[qf][j] += p;
            plds[wid][qf * 16 + 4 * g + j][nf * 16 + c15] = f2bf(p);
          }
        }
      }
      __asm__ volatile("s_waitcnt lgkmcnt(0)" ::: "memory");
#pragma unroll
      for (int qf = 0; qf < 2; ++qf) {
        const bf16x8 pa = *reinterpret_cast<const bf16x8*>(&plds[wid][qf * 16 + c15][g * 8]);
#pragma unroll
        for (int dvf = 0; dvf < 2; ++dvf) {
          const bf16x8 vb = *reinterpret_cast<const bf16x8*>(&vst[dvf * 16 + c15][nl0 + g * 8]);
          acc[qf][dvf] = __builtin_amdgcn_mfma_f32_16x16x32_bf16(pa, vb, acc[qf][dvf], 0, 0, 0);
        }
      }
    }
    __syncthreads();
  }

  // lsum: reduce across the 16 lanes of each group
#pragma unroll
  for (int qf = 0; qf < 2; ++qf)
#pragma unroll
    for (int j = 0; j < 4; ++j) {
      float v = lsum[qf][j];
      v += __shfl_xor(v, 1, 64);
      v += __shfl_xor(v, 2, 64);
      v += __shfl_xor(v, 4, 64);
      v += __shfl_xor(v, 8, 64);
      lsum[qf][j] = v;
    }

  float* cp = ctx_part + ((size_t)(b * H_ + h) * NC_ + nc) * Q_ * D_;
#pragma unroll
  for (int qf = 0; qf < 2; ++qf)
#pragma unroll
    for (int dvf = 0; dvf < 2; ++dvf)
#pragma unroll
      for (int j = 0; j < 4; ++j) {
        const int q = qw0 + qf * 16 + 4 * g + j;
        cp[(size_t)q * D_ + dvf * 16 + c15] = acc[qf][dvf][j];
      }
  if (c15 == 0) {
    float* lp = lsum_part + ((size_t)(b * H_ + h) * NC_ + nc) * Q_;
#pragma unroll
    for (int qf = 0; qf < 2; ++qf)
#pragma unroll
      for (int j = 0; j < 4; ++j) lp[qw0 + qf * 16 + 4 * g + j] = lsum[qf][j];
  }
}

// ---------------------------------------------------------------------------
// Kernel 5: combine partials + out_proj + residual + LayerNorm.
// One block per (b,q) row, fp32 throughout.
// ---------------------------------------------------------------------------
__global__ __launch_bounds__(256) void epilogue(const float* __restrict__ ctx_part,
                                                const float* __restrict__ lsum_part,
                                                const float* __restrict__ queries,
                                                const float* __restrict__ wo,
                                                const float* __restrict__ bo,
                                                const float* __restrict__ gamma,
                                                const float* __restrict__ beta,
                                                float* __restrict__ out) {
  const int bq = blockIdx.x;
  const int b = bq >> 8, q = bq & 255;
  const int t = threadIdx.x;
  const int h = t >> 5, dv = t & 31;
  float cs = 0.f, ls = 0.f;
  for (int k = 0; k < NC_; ++k) {
    cs += ctx_part[(((size_t)(b * H_ + h) * NC_ + k) * Q_ + q) * D_ + dv];
    ls += lsum_part[((size_t)(b * H_ + h) * NC_ + k) * Q_ + q];
  }
  __shared__ float ctxrow[C_];
  ctxrow[t] = cs / ls;
  __syncthreads();
  const float* wr = wo + (size_t)t * C_;
  float acc = bo[t];
#pragma unroll 8
  for (int j = 0; j < C_; ++j) acc = fmaf(ctxrow[j], wr[j], acc);
  const float x = queries[(size_t)bq * C_ + t] + acc;
  float s1 = x, s2 = x * x;
  for (int o = 32; o > 0; o >>= 1) {
    s1 += __shfl_down(s1, o, 64);
    s2 += __shfl_down(s2, o, 64);
  }
  __shared__ float r1[4], r2[4];
  if ((t & 63) == 0) { r1[t >> 6] = s1; r2[t >> 6] = s2; }
  __syncthreads();
  const float mu = (r1[0] + r1[1] + r1[2] + r1[3]) * (1.0f / C_);
  const float e2 = (r2[0] + r2[1] + r2[2] + r2[3]) * (1.0f / C_);
  const float var = e2 - mu * mu;
  out[(size_t)bq * C_ + t] = (x - mu) * rsqrtf(var + 1e-5f) * gamma[t] + beta[t];
}

extern "C" void kernel_launch(void* const* d_in, const int* in_sizes, int n_in,
                              void* d_out, int out_size, void* d_ws, size_t ws_size,
                              hipStream_t stream) {
  const float* queries    = (const float*)d_in[0];
  const float* vidfeat    = (const float*)d_in[1];
  const float* vidmask    = (const float*)d_in[2];
  const float* posembed   = (const float*)d_in[3];
  const float* queryembed = (const float*)d_in[4];
  const float* inw        = (const float*)d_in[5];
  const float* inb        = (const float*)d_in[6];
  const float* outw       = (const float*)d_in[7];
  const float* outb       = (const float*)d_in[8];
  const float* gamma      = (const float*)d_in[9];
  const float* beta       = (const float*)d_in[10];
  float* out = (float*)d_out;

  char* ws = (char*)d_ws;
  size_t off = 0;
  uint16_t* Qb = (uint16_t*)(ws + off); off += (size_t)B_ * H_ * Q_ * D_ * 2;    // 256 KB
  uint16_t* Kb = (uint16_t*)(ws + off); off += (size_t)B_ * N_ * C_ * 2;         // 16.78 MB
  uint16_t* Vb = (uint16_t*)(ws + off); off += (size_t)B_ * C_ * N_ * 2;         // 16.78 MB
  uint32_t* mb = (uint32_t*)(ws + off); off += (size_t)B_ * Q_ * (N_ / 32) * 4;  // 1 MB
  float* ctxp  = (float*)(ws + off);    off += (size_t)B_ * H_ * NC_ * Q_ * D_ * 4;  // 16.78 MB
  float* lsump = (float*)(ws + off);    off += (size_t)B_ * H_ * NC_ * Q_ * 4;       // 1 MB

  pack_mask<<<dim3(B_ * Q_), dim3(256), 0, stream>>>(vidmask, mb);
  qproj<<<dim3(B_ * Q_), dim3(256), 0, stream>>>(queries, queryembed, inw, inb, Qb);
  kvproj<<<dim3(B_ * 2 * (N_ / 128)), dim3(512), 0, stream>>>(vidfeat, posembed, inw, inb, Kb, Vb);
  attn<<<dim3(B_ * H_ * NC_), dim3(512), 0, stream>>>(Qb, Kb, Vb, mb, ctxp, lsump);
  epilogue<<<dim3(B_ * Q_), dim3(256), 0, stream>>>(ctxp, lsump, queries, outw, outb, gamma, beta, out);
}

// Round 2
// 131.603 us; speedup vs baseline: 1.2199x; 1.2199x over previous
//
#include <hip/hip_runtime.h>
#include <stdint.h>

// CrossAttentionLayer: B=2, Q=256, N=16384, C=256, H=8, d=32
#define B_ 2
#define Q_ 256
#define N_ 16384
#define C_ 256
#define H_ 8
#define D_ 32
#define NC_ 32                      // attention split-N chunks (N/NC = 512 per block)
#define SCALE 0.17677669529663687f  // 1/sqrt(32)

typedef __bf16 bf16x8 __attribute__((ext_vector_type(8)));
typedef float f32x4 __attribute__((ext_vector_type(4)));

__device__ __forceinline__ uint16_t f2bf(float f) {
  union { float f; uint32_t u; } c; c.f = f;
  uint32_t r = c.u + 0x7FFFu + ((c.u >> 16) & 1u);  // RNE
  return (uint16_t)(r >> 16);
}

// ---------------------------------------------------------------------------
// Kernel 0: convert K/V projection weights (in_proj_w rows 256..767) to bf16,
// row-major [512][256]: first 256 rows = wk, next 256 = wv.
// ---------------------------------------------------------------------------
__global__ __launch_bounds__(256) void wprep(const float* __restrict__ w,
                                             uint16_t* __restrict__ wb) {
  const int i = (blockIdx.x * 256 + threadIdx.x) * 8;
  const float* src = w + 256 * C_ + i;
  float4 a = *reinterpret_cast<const float4*>(src);
  float4 b = *reinterpret_cast<const float4*>(src + 4);
  ushort4 lo = {f2bf(a.x), f2bf(a.y), f2bf(a.z), f2bf(a.w)};
  ushort4 hi = {f2bf(b.x), f2bf(b.y), f2bf(b.z), f2bf(b.w)};
  *reinterpret_cast<ushort4*>(wb + i) = lo;
  *reinterpret_cast<ushort4*>(wb + i + 4) = hi;
}

// ---------------------------------------------------------------------------
// Kernel 1: pack vid_mask (B,Q,N) fp32 -> bitmask (B,Q,N/32), bit=1 => blocked.
// Applies the all-blocked fallback (row fully blocked -> clear all bits).
// ---------------------------------------------------------------------------
__global__ __launch_bounds__(256) void pack_mask(const float* __restrict__ vm,
                                                 uint32_t* __restrict__ mb) {
  const int bq = blockIdx.x;
  const float* row = vm + (size_t)bq * N_;
  __shared__ uint32_t words[N_ / 32];
  __shared__ int wcnt[4];
  __shared__ int tot;
  const int t = threadIdx.x;
  const int lane = t & 63;
  int cnt = 0;
  for (int i = 0; i < N_ / 256; ++i) {
    const int n = i * 256 + t;
    const bool blocked = row[n] < 0.5f;
    cnt += blocked ? 1 : 0;
    const unsigned long long bal = __ballot(blocked);
    if (lane == 0) {
      const int w0 = n >> 5;  // n is 64-aligned for lane 0
      words[w0] = (uint32_t)bal;
      words[w0 + 1] = (uint32_t)(bal >> 32);
    }
  }
  for (int o = 32; o > 0; o >>= 1) cnt += __shfl_down(cnt, o, 64);
  if (lane == 0) wcnt[t >> 6] = cnt;
  __syncthreads();
  if (t == 0) tot = wcnt[0] + wcnt[1] + wcnt[2] + wcnt[3];
  __syncthreads();
  const bool allb = (tot == N_);
  uint32_t* dst = mb + (size_t)bq * (N_ / 32);
  for (int i = t; i < N_ / 32; i += 256) dst[i] = allb ? 0u : words[i];
}

// ---------------------------------------------------------------------------
// Kernel 2: Q projection. q = ((queries+query_embed) @ wq^T + bq) * SCALE,
// stored bf16 as (B,H,Q,32). One block per (b,q) row.
// ---------------------------------------------------------------------------
__global__ __launch_bounds__(256) void qproj(const float* __restrict__ queries,
                                             const float* __restrict__ query_embed,
                                             const float* __restrict__ w,
                                             const float* __restrict__ bias,
                                             uint16_t* __restrict__ Qb) {
  const int bq = blockIdx.x;
  const int b = bq >> 8, q = bq & 255;
  __shared__ float x[C_];
  const int t = threadIdx.x;
  x[t] = queries[(size_t)bq * C_ + t] + query_embed[(size_t)bq * C_ + t];
  __syncthreads();
  const float* wr = w + (size_t)t * C_;  // wq row t (rows 0..255 of in_proj_w)
  float acc = bias[t];
#pragma unroll 8
  for (int j = 0; j < C_; ++j) acc = fmaf(x[j], wr[j], acc);
  acc *= SCALE;
  const int h = t >> 5, dk = t & 31;
  Qb[((size_t)(b * H_ + h) * Q_ + q) * D_ + dk] = f2bf(acc);
}

// ---------------------------------------------------------------------------
// Kernel 3: K/V projection GEMM, restructured (R1).
//   K' = wk @ (vf+pe) + bk  -> (B,N,C) bf16     V' = wv @ vf + bv -> (B,C,N)
// Tile: FULL cout (256) x 32 n per block  =>  activations read exactly once.
// 512 thr = 8 waves: waves 0-3 compute K (cout group wc*64), waves 4-7 V.
// Activations staged through LDS [n][cin] bf16 (pad 40), packed b32 writes.
// Weights read as bf16x8 from pre-converted wkv (L2-resident).
// ---------------------------------------------------------------------------
__global__ __launch_bounds__(512) void kvproj(const float* __restrict__ vf,
                                              const float* __restrict__ pe,
                                              const uint16_t* __restrict__ wkv,
                                              const float* __restrict__ bias,
                                              uint16_t* __restrict__ Kb,
                                              uint16_t* __restrict__ Vb) {
  const int bid = blockIdx.x;
  const int nb = bid & 511, b = bid >> 9;
  const int n0 = nb * 32;
  const int t = threadIdx.x, wid = t >> 6, lane = t & 63;
  const int g = lane >> 4, c15 = lane & 15;
  const int wc = wid & 3;
  const bool isV = wid >= 4;

  __shared__ __align__(16) uint16_t BKs[32][40];
  __shared__ __align__(16) uint16_t BVs[32][40];

  const float* X = vf + (size_t)b * C_ * N_;
  const float* P = pe + (size_t)b * C_ * N_;
  const uint16_t* W = wkv + (isV ? 256 * C_ : 0);
  const float* bs = bias + (isV ? 512 : 256);

  f32x4 acc[4][2];
#pragma unroll
  for (int cf = 0; cf < 4; ++cf) {
    f32x4 iv;
#pragma unroll
    for (int j = 0; j < 4; ++j) iv[j] = bs[wc * 64 + cf * 16 + 4 * g + j];
    acc[cf][0] = iv;
    acc[cf][1] = iv;
  }

  // staging map: thread -> (cin pair, n). 16 pairs x 32 n = 512 threads.
  const int cinp = t >> 5;   // 0..15  -> cin = 2*cinp, 2*cinp+1
  const int snn = t & 31;    // 0..31

  for (int cc = 0; cc < C_; cc += 32) {
    // issue global loads early (before barrier)
    const float x0 = X[(size_t)(cc + 2 * cinp) * N_ + n0 + snn];
    const float x1 = X[(size_t)(cc + 2 * cinp + 1) * N_ + n0 + snn];
    const float p0 = P[(size_t)(cc + 2 * cinp) * N_ + n0 + snn];
    const float p1 = P[(size_t)(cc + 2 * cinp + 1) * N_ + n0 + snn];
    bf16x8 A[4];
#pragma unroll
    for (int cf = 0; cf < 4; ++cf)
      A[cf] = *reinterpret_cast<const bf16x8*>(
          W + (size_t)(wc * 64 + cf * 16 + c15) * C_ + cc + g * 8);

    __syncthreads();  // previous step's LDS reads done
    const uint32_t wk = (uint32_t)f2bf(x0 + p0) | ((uint32_t)f2bf(x1 + p1) << 16);
    const uint32_t wv = (uint32_t)f2bf(x0) | ((uint32_t)f2bf(x1) << 16);
    *reinterpret_cast<uint32_t*>(&BKs[snn][2 * cinp]) = wk;
    *reinterpret_cast<uint32_t*>(&BVs[snn][2 * cinp]) = wv;
    __syncthreads();

    const uint16_t(*Bt)[40] = isV ? BVs : BKs;
    bf16x8 Bf[2];
#pragma unroll
    for (int nf = 0; nf < 2; ++nf)
      Bf[nf] = *reinterpret_cast<const bf16x8*>(&Bt[nf * 16 + c15][g * 8]);
#pragma unroll
    for (int cf = 0; cf < 4; ++cf)
#pragma unroll
      for (int nf = 0; nf < 2; ++nf)
        acc[cf][nf] = __builtin_amdgcn_mfma_f32_16x16x32_bf16(A[cf], Bf[nf], acc[cf][nf], 0, 0, 0);
  }

  if (!isV) {
    // K -> (B, N, C): lane holds 4 consecutive cout at fixed n -> 8B stores
    uint16_t* Kp = Kb + (size_t)b * N_ * C_;
#pragma unroll
    for (int cf = 0; cf < 4; ++cf)
#pragma unroll
      for (int nf = 0; nf < 2; ++nf) {
        uint2 pk;
        pk.x = (uint32_t)f2bf(acc[cf][nf][0]) | ((uint32_t)f2bf(acc[cf][nf][1]) << 16);
        pk.y = (uint32_t)f2bf(acc[cf][nf][2]) | ((uint32_t)f2bf(acc[cf][nf][3]) << 16);
        *reinterpret_cast<uint2*>(
            &Kp[(size_t)(n0 + nf * 16 + c15) * C_ + wc * 64 + cf * 16 + 4 * g]) = pk;
      }
  } else {
    // V -> (B, C, N): scalar stores, 16 consecutive n per 16-lane group
    uint16_t* Vp = Vb + (size_t)b * C_ * N_;
#pragma unroll
    for (int cf = 0; cf < 4; ++cf)
#pragma unroll
      for (int nf = 0; nf < 2; ++nf)
#pragma unroll
        for (int j = 0; j < 4; ++j) {
          const int cout = wc * 64 + cf * 16 + 4 * g + j;
          const int n = n0 + nf * 16 + c15;
          Vp[(size_t)cout * N_ + n] = f2bf(acc[cf][nf][j]);
        }
  }
}

// ---------------------------------------------------------------------------
// Kernel 4: attention over an N-chunk of 512 keys, all 256 queries of one
// (b, h). No max-tracking: P = exp(S) (masked -> 0), partials = unnormalized
// sum of P*V plus sum of P. Block: 512 thr = 8 waves, wave owns 32 q rows.
// ---------------------------------------------------------------------------
__global__ __launch_bounds__(512) void attn(const uint16_t* __restrict__ Qb,
                                            const uint16_t* __restrict__ Kb,
                                            const uint16_t* __restrict__ Vb,
                                            const uint32_t* __restrict__ mb,
                                            float* __restrict__ ctx_part,
                                            float* __restrict__ lsum_part) {
  const int bid = blockIdx.x;
  const int nc = bid & 31, h = (bid >> 5) & 7, b = bid >> 8;
  const int t = threadIdx.x, wid = t >> 6, lane = t & 63;
  const int g = lane >> 4, c15 = lane & 15;
  const int qw0 = wid * 32;
  const int nbase = nc * (N_ / NC_);  // 512-wide chunk

  __shared__ __align__(16) uint16_t kst[128][40];       // [n-local][dk]
  __shared__ __align__(16) uint16_t vst[32][136];       // [dv][n-local 128]
  __shared__ __align__(16) uint16_t plds[8][32][40];    // per-wave P tile

  const uint16_t* Qp = Qb + (size_t)(b * H_ + h) * Q_ * D_;
  bf16x8 qfr[2];
#pragma unroll
  for (int qf = 0; qf < 2; ++qf)
    qfr[qf] = *reinterpret_cast<const bf16x8*>(Qp + (size_t)(qw0 + qf * 16 + c15) * D_ + g * 8);

  f32x4 acc[2][2];
  const f32x4 zero4 = {0.f, 0.f, 0.f, 0.f};
#pragma unroll
  for (int qf = 0; qf < 2; ++qf)
#pragma unroll
    for (int dvf = 0; dvf < 2; ++dvf) acc[qf][dvf] = zero4;
  float lsum[2][4] = {};

  const uint32_t* mrow = mb + (size_t)b * Q_ * (N_ / 32);

  for (int ss = 0; ss < (N_ / NC_) / 128; ++ss) {  // 4 stage-steps of 128 n
    const int nstart = nbase + ss * 128;
    {  // stage K tile: 128 rows x 32 dk
      const int row = t >> 2, ch = t & 3;
      const uint4 vdat = *reinterpret_cast<const uint4*>(
          Kb + ((size_t)(b * N_ + nstart + row)) * C_ + h * D_ + ch * 8);
      *reinterpret_cast<uint4*>(&kst[row][ch * 8]) = vdat;
    }
    {  // stage V tile: 32 dv rows x 128 n
      const int row = t >> 4, ch = t & 15;
      const uint4 vdat = *reinterpret_cast<const uint4*>(
          Vb + ((size_t)(b * C_ + h * D_ + row)) * N_ + nstart + ch * 8);
      *reinterpret_cast<uint4*>(&vst[row][ch * 8]) = vdat;
    }
    __syncthreads();

#pragma unroll
    for (int sub = 0; sub < 4; ++sub) {  // 32 n per sub-step
      const int nl0 = sub * 32;
      bf16x8 kfr[2];
#pragma unroll
      for (int nf = 0; nf < 2; ++nf)
        kfr[nf] = *reinterpret_cast<const bf16x8*>(&kst[nl0 + nf * 16 + c15][g * 8]);
      f32x4 s[2][2];
#pragma unroll
      for (int qf = 0; qf < 2; ++qf)
#pragma unroll
        for (int nf = 0; nf < 2; ++nf)
          s[qf][nf] = __builtin_amdgcn_mfma_f32_16x16x32_bf16(qfr[qf], kfr[nf], zero4, 0, 0, 0);

      const int wofs = (nstart + nl0) >> 5;  // one 32-bit word covers this sub-step
#pragma unroll
      for (int qf = 0; qf < 2; ++qf) {
#pragma unroll
        for (int j = 0; j < 4; ++j) {
          const int q = qw0 + qf * 16 + 4 * g + j;
          const uint32_t wmask = mrow[(size_t)q * (N_ / 32) + wofs];
#pragma unroll
          for (int nf = 0; nf < 2; ++nf) {
            const int bit = nf * 16 + c15;
            const float p = ((wmask >> bit) & 1u) ? 0.0f : __expf(s[qf][nf][j]);
            lsum[qf][j] += p;
            plds[wid][qf * 16 + 4 * g + j][nf * 16 + c15] = f2bf(p);
          }
        }
      }
      __asm__ volatile("s_waitcnt lgkmcnt(0)" ::: "memory");
#pragma unroll
      for (int qf = 0; qf < 2; ++qf) {
        const bf16x8 pa = *reinterpret_cast<const bf16x8*>(&plds[wid][qf * 16 + c15][g * 8]);
#pragma unroll
        for (int dvf = 0; dvf < 2; ++dvf) {
          const bf16x8 vb = *reinterpret_cast<const bf16x8*>(&vst[dvf * 16 + c15][nl0 + g * 8]);
          acc[qf][dvf] = __builtin_amdgcn_mfma_f32_16x16x32_bf16(pa, vb, acc[qf][dvf], 0, 0, 0);
        }
      }
    }
    __syncthreads();
  }

  // lsum: reduce across the 16 lanes of each group
#pragma unroll
  for (int qf = 0; qf < 2; ++qf)
#pragma unroll
    for (int j = 0; j < 4; ++j) {
      float v = lsum[qf][j];
      v += __shfl_xor(v, 1, 64);
      v += __shfl_xor(v, 2, 64);
      v += __shfl_xor(v, 4, 64);
      v += __shfl_xor(v, 8, 64);
      lsum[qf][j] = v;
    }

  float* cp = ctx_part + ((size_t)(b * H_ + h) * NC_ + nc) * Q_ * D_;
#pragma unroll
  for (int qf = 0; qf < 2; ++qf)
#pragma unroll
    for (int dvf = 0; dvf < 2; ++dvf)
#pragma unroll
      for (int j = 0; j < 4; ++j) {
        const int q = qw0 + qf * 16 + 4 * g + j;
        cp[(size_t)q * D_ + dvf * 16 + c15] = acc[qf][dvf][j];
      }
  if (c15 == 0) {
    float* lp = lsum_part + ((size_t)(b * H_ + h) * NC_ + nc) * Q_;
#pragma unroll
    for (int qf = 0; qf < 2; ++qf)
#pragma unroll
      for (int j = 0; j < 4; ++j) lp[qw0 + qf * 16 + 4 * g + j] = lsum[qf][j];
  }
}

// ---------------------------------------------------------------------------
// Kernel 5: combine partials + out_proj + residual + LayerNorm.
// One block per (b,q) row, fp32 throughout.
// ---------------------------------------------------------------------------
__global__ __launch_bounds__(256) void epilogue(const float* __restrict__ ctx_part,
                                                const float* __restrict__ lsum_part,
                                                const float* __restrict__ queries,
                                                const float* __restrict__ wo,
                                                const float* __restrict__ bo,
                                                const float* __restrict__ gamma,
                                                const float* __restrict__ beta,
                                                float* __restrict__ out) {
  const int bq = blockIdx.x;
  const int b = bq >> 8, q = bq & 255;
  const int t = threadIdx.x;
  const int h = t >> 5, dv = t & 31;
  float cs = 0.f, ls = 0.f;
  for (int k = 0; k < NC_; ++k) {
    cs += ctx_part[(((size_t)(b * H_ + h) * NC_ + k) * Q_ + q) * D_ + dv];
    ls += lsum_part[((size_t)(b * H_ + h) * NC_ + k) * Q_ + q];
  }
  __shared__ float ctxrow[C_];
  ctxrow[t] = cs / ls;
  __syncthreads();
  const float* wr = wo + (size_t)t * C_;
  float acc = bo[t];
#pragma unroll 8
  for (int j = 0; j < C_; ++j) acc = fmaf(ctxrow[j], wr[j], acc);
  const float x = queries[(size_t)bq * C_ + t] + acc;
  float s1 = x, s2 = x * x;
  for (int o = 32; o > 0; o >>= 1) {
    s1 += __shfl_down(s1, o, 64);
    s2 += __shfl_down(s2, o, 64);
  }
  __shared__ float r1[4], r2[4];
  if ((t & 63) == 0) { r1[t >> 6] = s1; r2[t >> 6] = s2; }
  __syncthreads();
  const float mu = (r1[0] + r1[1] + r1[2] + r1[3]) * (1.0f / C_);
  const float e2 = (r2[0] + r2[1] + r2[2] + r2[3]) * (1.0f / C_);
  const float var = e2 - mu * mu;
  out[(size_t)bq * C_ + t] = (x - mu) * rsqrtf(var + 1e-5f) * gamma[t] + beta[t];
}

extern "C" void kernel_launch(void* const* d_in, const int* in_sizes, int n_in,
                              void* d_out, int out_size, void* d_ws, size_t ws_size,
                              hipStream_t stream) {
  const float* queries    = (const float*)d_in[0];
  const float* vidfeat    = (const float*)d_in[1];
  const float* vidmask    = (const float*)d_in[2];
  const float* posembed   = (const float*)d_in[3];
  const float* queryembed = (const float*)d_in[4];
  const float* inw        = (const float*)d_in[5];
  const float* inb        = (const float*)d_in[6];
  const float* outw       = (const float*)d_in[7];
  const float* outb       = (const float*)d_in[8];
  const float* gamma      = (const float*)d_in[9];
  const float* beta       = (const float*)d_in[10];
  float* out = (float*)d_out;

  char* ws = (char*)d_ws;
  size_t off = 0;
  uint16_t* Qb = (uint16_t*)(ws + off); off += (size_t)B_ * H_ * Q_ * D_ * 2;    // 256 KB
  uint16_t* Kb = (uint16_t*)(ws + off); off += (size_t)B_ * N_ * C_ * 2;         // 16.78 MB
  uint16_t* Vb = (uint16_t*)(ws + off); off += (size_t)B_ * C_ * N_ * 2;         // 16.78 MB
  uint32_t* mb = (uint32_t*)(ws + off); off += (size_t)B_ * Q_ * (N_ / 32) * 4;  // 1 MB
  float* ctxp  = (float*)(ws + off);    off += (size_t)B_ * H_ * NC_ * Q_ * D_ * 4;  // 16.78 MB
  float* lsump = (float*)(ws + off);    off += (size_t)B_ * H_ * NC_ * Q_ * 4;       // 1 MB
  uint16_t* wkv = (uint16_t*)(ws + off); off += (size_t)512 * C_ * 2;            // 256 KB

  wprep<<<dim3(64), dim3(256), 0, stream>>>(inw, wkv);
  pack_mask<<<dim3(B_ * Q_), dim3(256), 0, stream>>>(vidmask, mb);
  qproj<<<dim3(B_ * Q_), dim3(256), 0, stream>>>(queries, queryembed, inw, inb, Qb);
  kvproj<<<dim3(B_ * (N_ / 32)), dim3(512), 0, stream>>>(vidfeat, posembed, wkv, inb, Kb, Vb);
  attn<<<dim3(B_ * H_ * NC_), dim3(512), 0, stream>>>(Qb, Kb, Vb, mb, ctxp, lsump);
  epilogue<<<dim3(B_ * Q_), dim3(256), 0, stream>>>(ctxp, lsump, queries, outw, outb, gamma, beta, out);
}

// Round 3
// 124.543 us; speedup vs baseline: 1.2890x; 1.0567x over previous
//
#include <hip/hip_runtime.h>
#include <stdint.h>

// CrossAttentionLayer: B=2, Q=256, N=16384, C=256, H=8, d=32
#define B_ 2
#define Q_ 256
#define N_ 16384
#define C_ 256
#define H_ 8
#define D_ 32
#define NC_ 32                      // attention split-N chunks (N/NC = 512 per block)
#define SCALE 0.17677669529663687f  // 1/sqrt(32)

typedef __bf16 bf16x8 __attribute__((ext_vector_type(8)));
typedef float f32x4 __attribute__((ext_vector_type(4)));

__device__ __forceinline__ uint16_t f2bf(float f) {
  union { float f; uint32_t u; } c; c.f = f;
  uint32_t r = c.u + 0x7FFFu + ((c.u >> 16) & 1u);  // RNE
  return (uint16_t)(r >> 16);
}
__device__ __forceinline__ uint32_t pk2(float a, float b) {
  return (uint32_t)f2bf(a) | ((uint32_t)f2bf(b) << 16);
}

// ---------------------------------------------------------------------------
// Kernel 0: convert K/V projection weights (in_proj_w rows 256..767) to bf16,
// row-major [512][256]: first 256 rows = wk, next 256 = wv.
// ---------------------------------------------------------------------------
__global__ __launch_bounds__(256) void wprep(const float* __restrict__ w,
                                             uint16_t* __restrict__ wb) {
  const int i = (blockIdx.x * 256 + threadIdx.x) * 8;
  const float* src = w + 256 * C_ + i;
  float4 a = *reinterpret_cast<const float4*>(src);
  float4 b = *reinterpret_cast<const float4*>(src + 4);
  ushort4 lo = {f2bf(a.x), f2bf(a.y), f2bf(a.z), f2bf(a.w)};
  ushort4 hi = {f2bf(b.x), f2bf(b.y), f2bf(b.z), f2bf(b.w)};
  *reinterpret_cast<ushort4*>(wb + i) = lo;
  *reinterpret_cast<ushort4*>(wb + i + 4) = hi;
}

// ---------------------------------------------------------------------------
// Kernel 1: pack vid_mask (B,Q,N) fp32 -> bitmask (B,Q,N/32), bit=1 => blocked.
// ---------------------------------------------------------------------------
__global__ __launch_bounds__(256) void pack_mask(const float* __restrict__ vm,
                                                 uint32_t* __restrict__ mb) {
  const int bq = blockIdx.x;
  const float* row = vm + (size_t)bq * N_;
  __shared__ uint32_t words[N_ / 32];
  __shared__ int wcnt[4];
  __shared__ int tot;
  const int t = threadIdx.x;
  const int lane = t & 63;
  int cnt = 0;
  for (int i = 0; i < N_ / 256; ++i) {
    const int n = i * 256 + t;
    const bool blocked = row[n] < 0.5f;
    cnt += blocked ? 1 : 0;
    const unsigned long long bal = __ballot(blocked);
    if (lane == 0) {
      const int w0 = n >> 5;
      words[w0] = (uint32_t)bal;
      words[w0 + 1] = (uint32_t)(bal >> 32);
    }
  }
  for (int o = 32; o > 0; o >>= 1) cnt += __shfl_down(cnt, o, 64);
  if (lane == 0) wcnt[t >> 6] = cnt;
  __syncthreads();
  if (t == 0) tot = wcnt[0] + wcnt[1] + wcnt[2] + wcnt[3];
  __syncthreads();
  const bool allb = (tot == N_);
  uint32_t* dst = mb + (size_t)bq * (N_ / 32);
  for (int i = t; i < N_ / 32; i += 256) dst[i] = allb ? 0u : words[i];
}

// ---------------------------------------------------------------------------
// Kernel 2: Q projection -> (B,H,Q,32) bf16, pre-scaled by 1/sqrt(d).
// ---------------------------------------------------------------------------
__global__ __launch_bounds__(256) void qproj(const float* __restrict__ queries,
                                             const float* __restrict__ query_embed,
                                             const float* __restrict__ w,
                                             const float* __restrict__ bias,
                                             uint16_t* __restrict__ Qb) {
  const int bq = blockIdx.x;
  const int b = bq >> 8, q = bq & 255;
  __shared__ float x[C_];
  const int t = threadIdx.x;
  x[t] = queries[(size_t)bq * C_ + t] + query_embed[(size_t)bq * C_ + t];
  __syncthreads();
  const float* wr = w + (size_t)t * C_;
  float acc = bias[t];
#pragma unroll 8
  for (int j = 0; j < C_; ++j) acc = fmaf(x[j], wr[j], acc);
  acc *= SCALE;
  const int h = t >> 5, dk = t & 31;
  Qb[((size_t)(b * H_ + h) * Q_ + q) * D_ + dk] = f2bf(acc);
}

// ---------------------------------------------------------------------------
// Kernel 3 (R2 rewrite): K/V projection GEMM, pipelined.
//   K' = wk @ (vf+pe) + bk  -> (B,N,C) bf16     V' = wv @ vf + bv -> (B,C,N)
// Tile: 256 cout x 64 n per block, grid 512 (2 blocks/CU). 8 waves:
// waves 0-3 compute K (D[row=cout][col=n]), waves 4-7 compute V TRANSPOSED
// (D[row=n][col=cout]) so both epilogues are packed 8B stores.
// Pipeline: reg-prefetch (T14) + double-buffered LDS, ONE barrier per step.
// LDS tiles [64 n][32 cin] bf16 with 16B-block XOR swizzle (<=2-way conflicts).
// ---------------------------------------------------------------------------
__global__ __launch_bounds__(512) void kvproj(const float* __restrict__ vf,
                                              const float* __restrict__ pe,
                                              const uint16_t* __restrict__ wkv,
                                              const float* __restrict__ bias,
                                              uint16_t* __restrict__ Kb,
                                              uint16_t* __restrict__ Vb) {
  const int bid = blockIdx.x;
  const int nb = bid & 255, b = bid >> 8;
  const int n0 = nb * 64;
  const int t = threadIdx.x, wid = t >> 6, lane = t & 63;
  const int g = lane >> 4, c15 = lane & 15;
  const int wq = wid & 3;
  const bool isV = wid >= 4;

  __shared__ __align__(16) uint16_t Ks[2][64][40];
  __shared__ __align__(16) uint16_t Vs[2][64][40];

  const float* X = vf + (size_t)b * C_ * N_;
  const float* P = pe + (size_t)b * C_ * N_;
  // K-wave A-rows / V-wave B-rows both read wkv row (section + wq*64+cf*16+c15)
  const uint16_t* Wbase = wkv + (isV ? 256 * C_ : 0) + (size_t)(wq * 64 + c15) * C_;

  f32x4 acc[4][4];
  if (!isV) {
#pragma unroll
    for (int cf = 0; cf < 4; ++cf) {
      f32x4 iv;
#pragma unroll
      for (int j = 0; j < 4; ++j) iv[j] = bias[256 + wq * 64 + cf * 16 + 4 * g + j];
#pragma unroll
      for (int nf = 0; nf < 4; ++nf) acc[cf][nf] = iv;
    }
  } else {
#pragma unroll
    for (int cf = 0; cf < 4; ++cf) {
      const float bv = bias[512 + wq * 64 + cf * 16 + c15];
      const f32x4 iv = {bv, bv, bv, bv};
#pragma unroll
      for (int nf = 0; nf < 4; ++nf) acc[nf][cf] = iv;
    }
  }

  // staging map: thread -> cin pair (2*c2, 2*c2+1) x n pair (2*n2, 2*n2+1)
  const int c2 = t >> 5, n2 = t & 31;
  const float* Xp = X + (size_t)(2 * c2) * N_ + n0 + 2 * n2;
  const float* Pp = P + (size_t)(2 * c2) * N_ + n0 + 2 * n2;
  // swizzled element offset for the cin-pair column (16B-block-preserving XOR)
  const int cw2 = (c2 ^ (4 * ((n2 >> 2) & 3))) * 2;

  float2 x0 = *(const float2*)(Xp);
  float2 x1 = *(const float2*)(Xp + N_);
  float2 p0 = *(const float2*)(Pp);
  float2 p1 = *(const float2*)(Pp + N_);

  int cur = 0;
  for (int s = 0; s < 8; ++s) {
    const int cc = s * 32;
    bf16x8 Wf[4];  // issue L2 weight loads early
#pragma unroll
    for (int cf = 0; cf < 4; ++cf)
      Wf[cf] = *(const bf16x8*)(Wbase + (size_t)cf * 16 * C_ + cc + g * 8);

    // stage current step from regs (loaded last iteration)
    *(uint32_t*)&Ks[cur][2 * n2][cw2]     = pk2(x0.x + p0.x, x1.x + p1.x);
    *(uint32_t*)&Ks[cur][2 * n2 + 1][cw2] = pk2(x0.y + p0.y, x1.y + p1.y);
    *(uint32_t*)&Vs[cur][2 * n2][cw2]     = pk2(x0.x, x1.x);
    *(uint32_t*)&Vs[cur][2 * n2 + 1][cw2] = pk2(x0.y, x1.y);

    if (s < 7) {  // prefetch next step (latency hides under barrier+MFMA)
      const float* xn = Xp + (size_t)(cc + 32) * N_;
      const float* pn = Pp + (size_t)(cc + 32) * N_;
      x0 = *(const float2*)(xn);
      x1 = *(const float2*)(xn + N_);
      p0 = *(const float2*)(pn);
      p1 = *(const float2*)(pn + N_);
    }
    __syncthreads();

    if (!isV) {
#pragma unroll
      for (int nf = 0; nf < 4; ++nf) {
        const int r = nf * 16 + c15;
        const bf16x8 Bf = *(const bf16x8*)&Ks[cur][r][8 * (g ^ ((r >> 3) & 3))];
#pragma unroll
        for (int cf = 0; cf < 4; ++cf)
          acc[cf][nf] = __builtin_amdgcn_mfma_f32_16x16x32_bf16(Wf[cf], Bf, acc[cf][nf], 0, 0, 0);
      }
    } else {
#pragma unroll
      for (int nf = 0; nf < 4; ++nf) {
        const int r = nf * 16 + c15;
        const bf16x8 Af = *(const bf16x8*)&Vs[cur][r][8 * (g ^ ((r >> 3) & 3))];
#pragma unroll
        for (int cf = 0; cf < 4; ++cf)
          acc[nf][cf] = __builtin_amdgcn_mfma_f32_16x16x32_bf16(Af, Wf[cf], acc[nf][cf], 0, 0, 0);
      }
    }
    cur ^= 1;
  }

  if (!isV) {
    // K -> (B,N,C): lane holds 4 consecutive cout (j) at n = nf*16+c15
    uint16_t* Kp = Kb + (size_t)b * N_ * C_;
#pragma unroll
    for (int cf = 0; cf < 4; ++cf)
#pragma unroll
      for (int nf = 0; nf < 4; ++nf) {
        uint2 pkv;
        pkv.x = pk2(acc[cf][nf][0], acc[cf][nf][1]);
        pkv.y = pk2(acc[cf][nf][2], acc[cf][nf][3]);
        *(uint2*)&Kp[(size_t)(n0 + nf * 16 + c15) * C_ + wq * 64 + cf * 16 + 4 * g] = pkv;
      }
  } else {
    // V -> (B,C,N): lane holds 4 consecutive n (j) at cout = wq*64+cf*16+c15
    uint16_t* Vp = Vb + (size_t)b * C_ * N_;
#pragma unroll
    for (int nf = 0; nf < 4; ++nf)
#pragma unroll
      for (int cf = 0; cf < 4; ++cf) {
        uint2 pkv;
        pkv.x = pk2(acc[nf][cf][0], acc[nf][cf][1]);
        pkv.y = pk2(acc[nf][cf][2], acc[nf][cf][3]);
        *(uint2*)&Vp[(size_t)(wq * 64 + cf * 16 + c15) * N_ + n0 + nf * 16 + 4 * g] = pkv;
      }
  }
}

// ---------------------------------------------------------------------------
// Kernel 4: attention over an N-chunk of 512 keys (unchanged this round).
// ---------------------------------------------------------------------------
__global__ __launch_bounds__(512) void attn(const uint16_t* __restrict__ Qb,
                                            const uint16_t* __restrict__ Kb,
                                            const uint16_t* __restrict__ Vb,
                                            const uint32_t* __restrict__ mb,
                                            float* __restrict__ ctx_part,
                                            float* __restrict__ lsum_part) {
  const int bid = blockIdx.x;
  const int nc = bid & 31, h = (bid >> 5) & 7, b = bid >> 8;
  const int t = threadIdx.x, wid = t >> 6, lane = t & 63;
  const int g = lane >> 4, c15 = lane & 15;
  const int qw0 = wid * 32;
  const int nbase = nc * (N_ / NC_);

  __shared__ __align__(16) uint16_t kst[128][40];
  __shared__ __align__(16) uint16_t vst[32][136];
  __shared__ __align__(16) uint16_t plds[8][32][40];

  const uint16_t* Qp = Qb + (size_t)(b * H_ + h) * Q_ * D_;
  bf16x8 qfr[2];
#pragma unroll
  for (int qf = 0; qf < 2; ++qf)
    qfr[qf] = *reinterpret_cast<const bf16x8*>(Qp + (size_t)(qw0 + qf * 16 + c15) * D_ + g * 8);

  f32x4 acc[2][2];
  const f32x4 zero4 = {0.f, 0.f, 0.f, 0.f};
#pragma unroll
  for (int qf = 0; qf < 2; ++qf)
#pragma unroll
    for (int dvf = 0; dvf < 2; ++dvf) acc[qf][dvf] = zero4;
  float lsum[2][4] = {};

  const uint32_t* mrow = mb + (size_t)b * Q_ * (N_ / 32);

  for (int ss = 0; ss < (N_ / NC_) / 128; ++ss) {
    const int nstart = nbase + ss * 128;
    {
      const int row = t >> 2, ch = t & 3;
      const uint4 vdat = *reinterpret_cast<const uint4*>(
          Kb + ((size_t)(b * N_ + nstart + row)) * C_ + h * D_ + ch * 8);
      *reinterpret_cast<uint4*>(&kst[row][ch * 8]) = vdat;
    }
    {
      const int row = t >> 4, ch = t & 15;
      const uint4 vdat = *reinterpret_cast<const uint4*>(
          Vb + ((size_t)(b * C_ + h * D_ + row)) * N_ + nstart + ch * 8);
      *reinterpret_cast<uint4*>(&vst[row][ch * 8]) = vdat;
    }
    __syncthreads();

#pragma unroll
    for (int sub = 0; sub < 4; ++sub) {
      const int nl0 = sub * 32;
      bf16x8 kfr[2];
#pragma unroll
      for (int nf = 0; nf < 2; ++nf)
        kfr[nf] = *reinterpret_cast<const bf16x8*>(&kst[nl0 + nf * 16 + c15][g * 8]);
      f32x4 s[2][2];
#pragma unroll
      for (int qf = 0; qf < 2; ++qf)
#pragma unroll
        for (int nf = 0; nf < 2; ++nf)
          s[qf][nf] = __builtin_amdgcn_mfma_f32_16x16x32_bf16(qfr[qf], kfr[nf], zero4, 0, 0, 0);

      const int wofs = (nstart + nl0) >> 5;
#pragma unroll
      for (int qf = 0; qf < 2; ++qf) {
#pragma unroll
        for (int j = 0; j < 4; ++j) {
          const int q = qw0 + qf * 16 + 4 * g + j;
          const uint32_t wmask = mrow[(size_t)q * (N_ / 32) + wofs];
#pragma unroll
          for (int nf = 0; nf < 2; ++nf) {
            const int bit = nf * 16 + c15;
            const float p = ((wmask >> bit) & 1u) ? 0.0f : __expf(s[qf][nf][j]);
            lsum[qf][j] += p;
            plds[wid][qf * 16 + 4 * g + j][nf * 16 + c15] = f2bf(p);
          }
        }
      }
      __asm__ volatile("s_waitcnt lgkmcnt(0)" ::: "memory");
#pragma unroll
      for (int qf = 0; qf < 2; ++qf) {
        const bf16x8 pa = *reinterpret_cast<const bf16x8*>(&plds[wid][qf * 16 + c15][g * 8]);
#pragma unroll
        for (int dvf = 0; dvf < 2; ++dvf) {
          const bf16x8 vb = *reinterpret_cast<const bf16x8*>(&vst[dvf * 16 + c15][nl0 + g * 8]);
          acc[qf][dvf] = __builtin_amdgcn_mfma_f32_16x16x32_bf16(pa, vb, acc[qf][dvf], 0, 0, 0);
        }
      }
    }
    __syncthreads();
  }

#pragma unroll
  for (int qf = 0; qf < 2; ++qf)
#pragma unroll
    for (int j = 0; j < 4; ++j) {
      float v = lsum[qf][j];
      v += __shfl_xor(v, 1, 64);
      v += __shfl_xor(v, 2, 64);
      v += __shfl_xor(v, 4, 64);
      v += __shfl_xor(v, 8, 64);
      lsum[qf][j] = v;
    }

  float* cp = ctx_part + ((size_t)(b * H_ + h) * NC_ + nc) * Q_ * D_;
#pragma unroll
  for (int qf = 0; qf < 2; ++qf)
#pragma unroll
    for (int dvf = 0; dvf < 2; ++dvf)
#pragma unroll
      for (int j = 0; j < 4; ++j) {
        const int q = qw0 + qf * 16 + 4 * g + j;
        cp[(size_t)q * D_ + dvf * 16 + c15] = acc[qf][dvf][j];
      }
  if (c15 == 0) {
    float* lp = lsum_part + ((size_t)(b * H_ + h) * NC_ + nc) * Q_;
#pragma unroll
    for (int qf = 0; qf < 2; ++qf)
#pragma unroll
      for (int j = 0; j < 4; ++j) lp[qw0 + qf * 16 + 4 * g + j] = lsum[qf][j];
  }
}

// ---------------------------------------------------------------------------
// Kernel 5: combine partials + out_proj + residual + LayerNorm.
// ---------------------------------------------------------------------------
__global__ __launch_bounds__(256) void epilogue(const float* __restrict__ ctx_part,
                                                const float* __restrict__ lsum_part,
                                                const float* __restrict__ queries,
                                                const float* __restrict__ wo,
                                                const float* __restrict__ bo,
                                                const float* __restrict__ gamma,
                                                const float* __restrict__ beta,
                                                float* __restrict__ out) {
  const int bq = blockIdx.x;
  const int b = bq >> 8, q = bq & 255;
  const int t = threadIdx.x;
  const int h = t >> 5, dv = t & 31;
  float cs = 0.f, ls = 0.f;
  for (int k = 0; k < NC_; ++k) {
    cs += ctx_part[(((size_t)(b * H_ + h) * NC_ + k) * Q_ + q) * D_ + dv];
    ls += lsum_part[((size_t)(b * H_ + h) * NC_ + k) * Q_ + q];
  }
  __shared__ float ctxrow[C_];
  ctxrow[t] = cs / ls;
  __syncthreads();
  const float* wr = wo + (size_t)t * C_;
  float acc = bo[t];
#pragma unroll 8
  for (int j = 0; j < C_; ++j) acc = fmaf(ctxrow[j], wr[j], acc);
  const float x = queries[(size_t)bq * C_ + t] + acc;
  float s1 = x, s2 = x * x;
  for (int o = 32; o > 0; o >>= 1) {
    s1 += __shfl_down(s1, o, 64);
    s2 += __shfl_down(s2, o, 64);
  }
  __shared__ float r1[4], r2[4];
  if ((t & 63) == 0) { r1[t >> 6] = s1; r2[t >> 6] = s2; }
  __syncthreads();
  const float mu = (r1[0] + r1[1] + r1[2] + r1[3]) * (1.0f / C_);
  const float e2 = (r2[0] + r2[1] + r2[2] + r2[3]) * (1.0f / C_);
  const float var = e2 - mu * mu;
  out[(size_t)bq * C_ + t] = (x - mu) * rsqrtf(var + 1e-5f) * gamma[t] + beta[t];
}

extern "C" void kernel_launch(void* const* d_in, const int* in_sizes, int n_in,
                              void* d_out, int out_size, void* d_ws, size_t ws_size,
                              hipStream_t stream) {
  const float* queries    = (const float*)d_in[0];
  const float* vidfeat    = (const float*)d_in[1];
  const float* vidmask    = (const float*)d_in[2];
  const float* posembed   = (const float*)d_in[3];
  const float* queryembed = (const float*)d_in[4];
  const float* inw        = (const float*)d_in[5];
  const float* inb        = (const float*)d_in[6];
  const float* outw       = (const float*)d_in[7];
  const float* outb       = (const float*)d_in[8];
  const float* gamma      = (const float*)d_in[9];
  const float* beta       = (const float*)d_in[10];
  float* out = (float*)d_out;

  char* ws = (char*)d_ws;
  size_t off = 0;
  uint16_t* Qb = (uint16_t*)(ws + off); off += (size_t)B_ * H_ * Q_ * D_ * 2;
  uint16_t* Kb = (uint16_t*)(ws + off); off += (size_t)B_ * N_ * C_ * 2;
  uint16_t* Vb = (uint16_t*)(ws + off); off += (size_t)B_ * C_ * N_ * 2;
  uint32_t* mb = (uint32_t*)(ws + off); off += (size_t)B_ * Q_ * (N_ / 32) * 4;
  float* ctxp  = (float*)(ws + off);    off += (size_t)B_ * H_ * NC_ * Q_ * D_ * 4;
  float* lsump = (float*)(ws + off);    off += (size_t)B_ * H_ * NC_ * Q_ * 4;
  uint16_t* wkv = (uint16_t*)(ws + off); off += (size_t)512 * C_ * 2;

  wprep<<<dim3(64), dim3(256), 0, stream>>>(inw, wkv);
  pack_mask<<<dim3(B_ * Q_), dim3(256), 0, stream>>>(vidmask, mb);
  qproj<<<dim3(B_ * Q_), dim3(256), 0, stream>>>(queries, queryembed, inw, inb, Qb);
  kvproj<<<dim3(B_ * (N_ / 64)), dim3(512), 0, stream>>>(vidfeat, posembed, wkv, inb, Kb, Vb);
  attn<<<dim3(B_ * H_ * NC_), dim3(512), 0, stream>>>(Qb, Kb, Vb, mb, ctxp, lsump);
  epilogue<<<dim3(B_ * Q_), dim3(256), 0, stream>>>(ctxp, lsump, queries, outw, outb, gamma, beta, out);
}

// Round 4
// 115.348 us; speedup vs baseline: 1.3918x; 1.0797x over previous
//
#include <hip/hip_runtime.h>
#include <stdint.h>

// CrossAttentionLayer: B=2, Q=256, N=16384, C=256, H=8, d=32
#define B_ 2
#define Q_ 256
#define N_ 16384
#define C_ 256
#define H_ 8
#define D_ 32
#define NC_ 32                      // attention split-N chunks (N/NC = 512 per block)
#define SCALE 0.17677669529663687f  // 1/sqrt(32)

typedef __bf16 bf16x8 __attribute__((ext_vector_type(8)));
typedef float f32x4 __attribute__((ext_vector_type(4)));

__device__ __forceinline__ uint16_t f2bf(float f) {
  union { float f; uint32_t u; } c; c.f = f;
  uint32_t r = c.u + 0x7FFFu + ((c.u >> 16) & 1u);  // RNE
  return (uint16_t)(r >> 16);
}
__device__ __forceinline__ uint32_t pk2(float a, float b) {
  return (uint32_t)f2bf(a) | ((uint32_t)f2bf(b) << 16);
}
__device__ __forceinline__ void lgkm0_barrier() {
  __builtin_amdgcn_sched_barrier(0);
  asm volatile("s_waitcnt lgkmcnt(0)" ::: "memory");
  __builtin_amdgcn_sched_barrier(0);
  __builtin_amdgcn_s_barrier();
  __builtin_amdgcn_sched_barrier(0);
}

// ---------------------------------------------------------------------------
// Kernel 0a: convert K/V projection weights (in_proj_w rows 256..767) to bf16.
// ---------------------------------------------------------------------------
__global__ __launch_bounds__(256) void wprep(const float* __restrict__ w,
                                             uint16_t* __restrict__ wb) {
  const int i = (blockIdx.x * 256 + threadIdx.x) * 8;
  const float* src = w + 256 * C_ + i;
  float4 a = *reinterpret_cast<const float4*>(src);
  float4 b = *reinterpret_cast<const float4*>(src + 4);
  ushort4 lo = {f2bf(a.x), f2bf(a.y), f2bf(a.z), f2bf(a.w)};
  ushort4 hi = {f2bf(b.x), f2bf(b.y), f2bf(b.z), f2bf(b.w)};
  *reinterpret_cast<ushort4*>(wb + i) = lo;
  *reinterpret_cast<ushort4*>(wb + i + 4) = hi;
}

// ---------------------------------------------------------------------------
// Kernel 0b: 256x256 fp32 transpose (for wq and wo -> coalesced dot products).
// ---------------------------------------------------------------------------
__global__ __launch_bounds__(256) void transpose256(const float* __restrict__ src,
                                                    float* __restrict__ dst) {
  __shared__ float s[32][33];
  const int bx = blockIdx.x & 7, by = blockIdx.x >> 3;
  const int r0 = by * 32, c0 = bx * 32;
  const int tr = threadIdx.x >> 5, tc = threadIdx.x & 31;
#pragma unroll
  for (int k = 0; k < 4; ++k) s[tr + 8 * k][tc] = src[(size_t)(r0 + tr + 8 * k) * 256 + c0 + tc];
  __syncthreads();
#pragma unroll
  for (int k = 0; k < 4; ++k) dst[(size_t)(c0 + tr + 8 * k) * 256 + r0 + tc] = s[tc][tr + 8 * k];
}

// ---------------------------------------------------------------------------
// Kernel 1: pack vid_mask (B,Q,N) fp32 -> bitmask (B,Q,N/32), bit=1 => blocked.
// float4 loads + nibble packing via LDS.
// ---------------------------------------------------------------------------
__global__ __launch_bounds__(256) void pack_mask(const float* __restrict__ vm,
                                                 uint32_t* __restrict__ mb) {
  const int bq = blockIdx.x;
  const float* row = vm + (size_t)bq * N_;
  const int t = threadIdx.x, lane = t & 63;
  __shared__ uint8_t nib[16][256];
  __shared__ int wcnt[4];
  __shared__ int tot;
  int cnt = 0;
#pragma unroll
  for (int i = 0; i < 16; ++i) {
    const float4 v = *reinterpret_cast<const float4*>(&row[i * 1024 + 4 * t]);
    const uint32_t nb = (v.x < 0.5f ? 1u : 0u) | (v.y < 0.5f ? 2u : 0u) |
                        (v.z < 0.5f ? 4u : 0u) | (v.w < 0.5f ? 8u : 0u);
    nib[i][t] = (uint8_t)nb;
    cnt += __popc(nb);
  }
  for (int o = 32; o > 0; o >>= 1) cnt += __shfl_down(cnt, o, 64);
  if (lane == 0) wcnt[t >> 6] = cnt;
  __syncthreads();
  if (t == 0) tot = wcnt[0] + wcnt[1] + wcnt[2] + wcnt[3];
  __syncthreads();
  const bool allb = (tot == N_);
  uint32_t* dst = mb + (size_t)bq * 512;
#pragma unroll
  for (int k = 0; k < 2; ++k) {
    const int w = k * 256 + t;
    const int i = w >> 5, tw = w & 31;
    const uint2 u = *reinterpret_cast<const uint2*>(&nib[i][8 * tw]);
    uint32_t y0 = u.x & 0x0F0F0F0Fu; y0 = y0 | (y0 >> 4);
    uint32_t y1 = u.y & 0x0F0F0F0Fu; y1 = y1 | (y1 >> 4);
    const uint32_t word = (y0 & 0xFFu) | (((y0 >> 16) & 0xFFu) << 8) |
                          ((y1 & 0xFFu) << 16) | (((y1 >> 16) & 0xFFu) << 24);
    dst[w] = allb ? 0u : word;
  }
}

// ---------------------------------------------------------------------------
// Kernel 2: Q projection with TRANSPOSED weights (coalesced). 4 rows/block.
// ---------------------------------------------------------------------------
__global__ __launch_bounds__(256) void qproj(const float* __restrict__ queries,
                                             const float* __restrict__ query_embed,
                                             const float* __restrict__ wqT,
                                             const float* __restrict__ bias,
                                             uint16_t* __restrict__ Qb) {
  const int r0 = blockIdx.x * 4;
  const int t = threadIdx.x;
  __shared__ float x[4][C_];
#pragma unroll
  for (int r = 0; r < 4; ++r)
    x[r][t] = queries[(size_t)(r0 + r) * C_ + t] + query_embed[(size_t)(r0 + r) * C_ + t];
  __syncthreads();
  float a0 = bias[t], a1 = a0, a2 = a0, a3 = a0;
#pragma unroll 4
  for (int j = 0; j < C_; ++j) {
    const float wv = wqT[(size_t)j * C_ + t];
    a0 = fmaf(x[0][j], wv, a0);
    a1 = fmaf(x[1][j], wv, a1);
    a2 = fmaf(x[2][j], wv, a2);
    a3 = fmaf(x[3][j], wv, a3);
  }
  const int h = t >> 5, dk = t & 31;
  const float r4[4] = {a0, a1, a2, a3};
#pragma unroll
  for (int r = 0; r < 4; ++r) {
    const int bq = r0 + r;
    const int b = bq >> 8, q = bq & 255;
    Qb[((size_t)(b * H_ + h) * Q_ + q) * D_ + dk] = f2bf(r4[r] * SCALE);
  }
}

// ---------------------------------------------------------------------------
// Kernel 3: K/V projection GEMM. Raw-barrier pipeline: reg-staged LDS writes
// need only lgkmcnt(0) before s_barrier -> global prefetch stays in flight.
// ---------------------------------------------------------------------------
__global__ __launch_bounds__(512) void kvproj(const float* __restrict__ vf,
                                              const float* __restrict__ pe,
                                              const uint16_t* __restrict__ wkv,
                                              const float* __restrict__ bias,
                                              uint16_t* __restrict__ Kb,
                                              uint16_t* __restrict__ Vb) {
  const int bid = blockIdx.x;
  const int nb = bid & 255, b = bid >> 8;
  const int n0 = nb * 64;
  const int t = threadIdx.x, wid = t >> 6, lane = t & 63;
  const int g = lane >> 4, c15 = lane & 15;
  const int wq = wid & 3;
  const bool isV = wid >= 4;

  __shared__ __align__(16) uint16_t Ks[2][64][40];
  __shared__ __align__(16) uint16_t Vs[2][64][40];

  const float* X = vf + (size_t)b * C_ * N_;
  const float* P = pe + (size_t)b * C_ * N_;
  const uint16_t* Wbase = wkv + (isV ? 256 * C_ : 0) + (size_t)(wq * 64 + c15) * C_;

  f32x4 acc[4][4];
  if (!isV) {
#pragma unroll
    for (int cf = 0; cf < 4; ++cf) {
      f32x4 iv;
#pragma unroll
      for (int j = 0; j < 4; ++j) iv[j] = bias[256 + wq * 64 + cf * 16 + 4 * g + j];
#pragma unroll
      for (int nf = 0; nf < 4; ++nf) acc[cf][nf] = iv;
    }
  } else {
#pragma unroll
    for (int cf = 0; cf < 4; ++cf) {
      const float bv = bias[512 + wq * 64 + cf * 16 + c15];
      const f32x4 iv = {bv, bv, bv, bv};
#pragma unroll
      for (int nf = 0; nf < 4; ++nf) acc[nf][cf] = iv;
    }
  }

  const int c2 = t >> 5, n2 = t & 31;
  const float* Xp = X + (size_t)(2 * c2) * N_ + n0 + 2 * n2;
  const float* Pp = P + (size_t)(2 * c2) * N_ + n0 + 2 * n2;
  const int cw2 = (c2 ^ (4 * ((n2 >> 2) & 3))) * 2;

  float2 cx0 = *(const float2*)(Xp);
  float2 cx1 = *(const float2*)(Xp + N_);
  float2 cp0 = *(const float2*)(Pp);
  float2 cp1 = *(const float2*)(Pp + N_);

  int cur = 0;
  for (int s = 0; s < 8; ++s) {
    const int cc = s * 32;
    bf16x8 Wf[4];  // L2 weight fragments for this step
#pragma unroll
    for (int cf = 0; cf < 4; ++cf)
      Wf[cf] = *(const bf16x8*)(Wbase + (size_t)cf * 16 * C_ + cc + g * 8);

    // stage current step from regs (compiler inserts vmcnt wait here only)
    *(uint32_t*)&Ks[cur][2 * n2][cw2]     = pk2(cx0.x + cp0.x, cx1.x + cp1.x);
    *(uint32_t*)&Ks[cur][2 * n2 + 1][cw2] = pk2(cx0.y + cp0.y, cx1.y + cp1.y);
    *(uint32_t*)&Vs[cur][2 * n2][cw2]     = pk2(cx0.x, cx1.x);
    *(uint32_t*)&Vs[cur][2 * n2 + 1][cw2] = pk2(cx0.y, cx1.y);

    if (s < 7) {  // prefetch next step; stays in flight across the raw barrier
      const float* xn = Xp + (size_t)(cc + 32) * N_;
      const float* pn = Pp + (size_t)(cc + 32) * N_;
      cx0 = *(const float2*)(xn);
      cx1 = *(const float2*)(xn + N_);
      cp0 = *(const float2*)(pn);
      cp1 = *(const float2*)(pn + N_);
    }
    lgkm0_barrier();  // LDS writes visible; vmcnt NOT drained

    if (!isV) {
#pragma unroll
      for (int nf = 0; nf < 4; ++nf) {
        const int r = nf * 16 + c15;
        const bf16x8 Bf = *(const bf16x8*)&Ks[cur][r][8 * (g ^ ((r >> 3) & 3))];
#pragma unroll
        for (int cf = 0; cf < 4; ++cf)
          acc[cf][nf] = __builtin_amdgcn_mfma_f32_16x16x32_bf16(Wf[cf], Bf, acc[cf][nf], 0, 0, 0);
      }
    } else {
#pragma unroll
      for (int nf = 0; nf < 4; ++nf) {
        const int r = nf * 16 + c15;
        const bf16x8 Af = *(const bf16x8*)&Vs[cur][r][8 * (g ^ ((r >> 3) & 3))];
#pragma unroll
        for (int cf = 0; cf < 4; ++cf)
          acc[nf][cf] = __builtin_amdgcn_mfma_f32_16x16x32_bf16(Af, Wf[cf], acc[nf][cf], 0, 0, 0);
      }
    }
    __builtin_amdgcn_sched_barrier(0);
    cur ^= 1;
  }

  if (!isV) {
    uint16_t* Kp = Kb + (size_t)b * N_ * C_;
#pragma unroll
    for (int cf = 0; cf < 4; ++cf)
#pragma unroll
      for (int nf = 0; nf < 4; ++nf) {
        uint2 pkv;
        pkv.x = pk2(acc[cf][nf][0], acc[cf][nf][1]);
        pkv.y = pk2(acc[cf][nf][2], acc[cf][nf][3]);
        *(uint2*)&Kp[(size_t)(n0 + nf * 16 + c15) * C_ + wq * 64 + cf * 16 + 4 * g] = pkv;
      }
  } else {
    uint16_t* Vp = Vb + (size_t)b * C_ * N_;
#pragma unroll
    for (int nf = 0; nf < 4; ++nf)
#pragma unroll
      for (int cf = 0; cf < 4; ++cf) {
        uint2 pkv;
        pkv.x = pk2(acc[nf][cf][0], acc[nf][cf][1]);
        pkv.y = pk2(acc[nf][cf][2], acc[nf][cf][3]);
        *(uint2*)&Vp[(size_t)(wq * 64 + cf * 16 + c15) * N_ + n0 + nf * 16 + 4 * g] = pkv;
      }
  }
}

// ---------------------------------------------------------------------------
// Kernel 4: attention over an N-chunk of 512 keys. Raw-barrier double-buffered
// K/V staging (1 barrier per 128-key step, loads in flight); mask words
// batched per 64-key half.
// ---------------------------------------------------------------------------
__global__ __launch_bounds__(512) void attn(const uint16_t* __restrict__ Qb,
                                            const uint16_t* __restrict__ Kb,
                                            const uint16_t* __restrict__ Vb,
                                            const uint32_t* __restrict__ mb,
                                            float* __restrict__ ctx_part,
                                            float* __restrict__ lsum_part) {
  const int bid = blockIdx.x;
  const int nc = bid & 31, h = (bid >> 5) & 7, b = bid >> 8;
  const int t = threadIdx.x, wid = t >> 6, lane = t & 63;
  const int g = lane >> 4, c15 = lane & 15;
  const int qw0 = wid * 32;
  const int nbase = nc * (N_ / NC_);

  __shared__ __align__(16) uint16_t kst[2][128][40];
  __shared__ __align__(16) uint16_t vst[2][32][136];
  __shared__ __align__(16) uint16_t plds[8][32][40];

  const uint16_t* Qp = Qb + (size_t)(b * H_ + h) * Q_ * D_;
  bf16x8 qfr[2];
#pragma unroll
  for (int qf = 0; qf < 2; ++qf)
    qfr[qf] = *reinterpret_cast<const bf16x8*>(Qp + (size_t)(qw0 + qf * 16 + c15) * D_ + g * 8);

  f32x4 acc[2][2];
  const f32x4 zero4 = {0.f, 0.f, 0.f, 0.f};
#pragma unroll
  for (int qf = 0; qf < 2; ++qf)
#pragma unroll
    for (int dvf = 0; dvf < 2; ++dvf) acc[qf][dvf] = zero4;
  float lsum[2][4] = {};

  const uint32_t* mrow = mb + (size_t)b * Q_ * (N_ / 32);

  const int krow = t >> 2, kch = t & 3;
  const uint16_t* ksrc = Kb + ((size_t)(b * N_ + nbase + krow)) * C_ + h * D_ + kch * 8;
  const int vrow = t >> 4, vch = t & 15;
  const uint16_t* vsrc = Vb + ((size_t)(b * C_ + h * D_ + vrow)) * N_ + nbase + vch * 8;

  uint4 kreg = *(const uint4*)ksrc;
  uint4 vreg = *(const uint4*)vsrc;

  int cur = 0;
  for (int ss = 0; ss < 4; ++ss) {
    *(uint4*)&kst[cur][krow][kch * 8] = kreg;
    *(uint4*)&vst[cur][vrow][vch * 8] = vreg;
    if (ss < 3) {  // prefetch next step's K/V (in flight across barrier)
      kreg = *(const uint4*)(ksrc + (size_t)(ss + 1) * 128 * C_);
      vreg = *(const uint4*)(vsrc + (ss + 1) * 128);
    }
    lgkm0_barrier();

    const int nstart = nbase + ss * 128;
#pragma unroll
    for (int half = 0; half < 2; ++half) {
      uint32_t mw[2][4][2];
#pragma unroll
      for (int qf = 0; qf < 2; ++qf)
#pragma unroll
        for (int j = 0; j < 4; ++j) {
          const int q = qw0 + qf * 16 + 4 * g + j;
          const uint2 u = *reinterpret_cast<const uint2*>(
              &mrow[(size_t)q * (N_ / 32) + (nstart >> 5) + half * 2]);
          mw[qf][j][0] = u.x;
          mw[qf][j][1] = u.y;
        }
#pragma unroll
      for (int s2 = 0; s2 < 2; ++s2) {
        const int sub = half * 2 + s2;
        const int nl0 = sub * 32;
        bf16x8 kfr[2];
#pragma unroll
        for (int nf = 0; nf < 2; ++nf)
          kfr[nf] = *reinterpret_cast<const bf16x8*>(&kst[cur][nl0 + nf * 16 + c15][g * 8]);
        f32x4 s[2][2];
#pragma unroll
        for (int qf = 0; qf < 2; ++qf)
#pragma unroll
          for (int nf = 0; nf < 2; ++nf)
            s[qf][nf] = __builtin_amdgcn_mfma_f32_16x16x32_bf16(qfr[qf], kfr[nf], zero4, 0, 0, 0);

#pragma unroll
        for (int qf = 0; qf < 2; ++qf) {
#pragma unroll
          for (int j = 0; j < 4; ++j) {
            const uint32_t wmask = mw[qf][j][s2];
#pragma unroll
            for (int nf = 0; nf < 2; ++nf) {
              const int bit = nf * 16 + c15;
              const float p = ((wmask >> bit) & 1u) ? 0.0f : __expf(s[qf][nf][j]);
              lsum[qf][j] += p;
              plds[wid][qf * 16 + 4 * g + j][nf * 16 + c15] = f2bf(p);
            }
          }
        }
        __asm__ volatile("s_waitcnt lgkmcnt(0)" ::: "memory");
#pragma unroll
        for (int qf = 0; qf < 2; ++qf) {
          const bf16x8 pa = *reinterpret_cast<const bf16x8*>(&plds[wid][qf * 16 + c15][g * 8]);
#pragma unroll
          for (int dvf = 0; dvf < 2; ++dvf) {
            const bf16x8 vb =
                *reinterpret_cast<const bf16x8*>(&vst[cur][dvf * 16 + c15][nl0 + g * 8]);
            acc[qf][dvf] = __builtin_amdgcn_mfma_f32_16x16x32_bf16(pa, vb, acc[qf][dvf], 0, 0, 0);
          }
        }
      }
    }
    __builtin_amdgcn_sched_barrier(0);
    cur ^= 1;
  }

#pragma unroll
  for (int qf = 0; qf < 2; ++qf)
#pragma unroll
    for (int j = 0; j < 4; ++j) {
      float v = lsum[qf][j];
      v += __shfl_xor(v, 1, 64);
      v += __shfl_xor(v, 2, 64);
      v += __shfl_xor(v, 4, 64);
      v += __shfl_xor(v, 8, 64);
      lsum[qf][j] = v;
    }

  float* cp = ctx_part + ((size_t)(b * H_ + h) * NC_ + nc) * Q_ * D_;
#pragma unroll
  for (int qf = 0; qf < 2; ++qf)
#pragma unroll
    for (int dvf = 0; dvf < 2; ++dvf)
#pragma unroll
      for (int j = 0; j < 4; ++j) {
        const int q = qw0 + qf * 16 + 4 * g + j;
        cp[(size_t)q * D_ + dvf * 16 + c15] = acc[qf][dvf][j];
      }
  if (c15 == 0) {
    float* lp = lsum_part + ((size_t)(b * H_ + h) * NC_ + nc) * Q_;
#pragma unroll
    for (int qf = 0; qf < 2; ++qf)
#pragma unroll
      for (int j = 0; j < 4; ++j) lp[qw0 + qf * 16 + 4 * g + j] = lsum[qf][j];
  }
}

// ---------------------------------------------------------------------------
// Kernel 5: combine partials + out_proj (TRANSPOSED weights) + residual + LN.
// ---------------------------------------------------------------------------
__global__ __launch_bounds__(256) void epilogue(const float* __restrict__ ctx_part,
                                                const float* __restrict__ lsum_part,
                                                const float* __restrict__ queries,
                                                const float* __restrict__ woT,
                                                const float* __restrict__ bo,
                                                const float* __restrict__ gamma,
                                                const float* __restrict__ beta,
                                                float* __restrict__ out) {
  const int bq = blockIdx.x;
  const int b = bq >> 8, q = bq & 255;
  const int t = threadIdx.x;
  const int h = t >> 5, dv = t & 31;
  float cs = 0.f, ls = 0.f;
  for (int k = 0; k < NC_; ++k) {
    cs += ctx_part[(((size_t)(b * H_ + h) * NC_ + k) * Q_ + q) * D_ + dv];
    ls += lsum_part[((size_t)(b * H_ + h) * NC_ + k) * Q_ + q];
  }
  __shared__ float ctxrow[C_];
  ctxrow[t] = cs / ls;
  __syncthreads();
  float acc = bo[t];
#pragma unroll 8
  for (int j = 0; j < C_; ++j) acc = fmaf(ctxrow[j], woT[(size_t)j * C_ + t], acc);
  const float x = queries[(size_t)bq * C_ + t] + acc;
  float s1 = x, s2 = x * x;
  for (int o = 32; o > 0; o >>= 1) {
    s1 += __shfl_down(s1, o, 64);
    s2 += __shfl_down(s2, o, 64);
  }
  __shared__ float r1[4], r2[4];
  if ((t & 63) == 0) { r1[t >> 6] = s1; r2[t >> 6] = s2; }
  __syncthreads();
  const float mu = (r1[0] + r1[1] + r1[2] + r1[3]) * (1.0f / C_);
  const float e2 = (r2[0] + r2[1] + r2[2] + r2[3]) * (1.0f / C_);
  const float var = e2 - mu * mu;
  out[(size_t)bq * C_ + t] = (x - mu) * rsqrtf(var + 1e-5f) * gamma[t] + beta[t];
}

extern "C" void kernel_launch(void* const* d_in, const int* in_sizes, int n_in,
                              void* d_out, int out_size, void* d_ws, size_t ws_size,
                              hipStream_t stream) {
  const float* queries    = (const float*)d_in[0];
  const float* vidfeat    = (const float*)d_in[1];
  const float* vidmask    = (const float*)d_in[2];
  const float* posembed   = (const float*)d_in[3];
  const float* queryembed = (const float*)d_in[4];
  const float* inw        = (const float*)d_in[5];
  const float* inb        = (const float*)d_in[6];
  const float* outw       = (const float*)d_in[7];
  const float* outb       = (const float*)d_in[8];
  const float* gamma      = (const float*)d_in[9];
  const float* beta       = (const float*)d_in[10];
  float* out = (float*)d_out;

  char* ws = (char*)d_ws;
  size_t off = 0;
  uint16_t* Qb = (uint16_t*)(ws + off); off += (size_t)B_ * H_ * Q_ * D_ * 2;
  uint16_t* Kb = (uint16_t*)(ws + off); off += (size_t)B_ * N_ * C_ * 2;
  uint16_t* Vb = (uint16_t*)(ws + off); off += (size_t)B_ * C_ * N_ * 2;
  uint32_t* mb = (uint32_t*)(ws + off); off += (size_t)B_ * Q_ * (N_ / 32) * 4;
  float* ctxp  = (float*)(ws + off);    off += (size_t)B_ * H_ * NC_ * Q_ * D_ * 4;
  float* lsump = (float*)(ws + off);    off += (size_t)B_ * H_ * NC_ * Q_ * 4;
  uint16_t* wkv = (uint16_t*)(ws + off); off += (size_t)512 * C_ * 2;
  float* wqT   = (float*)(ws + off);    off += (size_t)C_ * C_ * 4;
  float* woT   = (float*)(ws + off);    off += (size_t)C_ * C_ * 4;

  wprep<<<dim3(64), dim3(256), 0, stream>>>(inw, wkv);
  transpose256<<<dim3(64), dim3(256), 0, stream>>>(inw, wqT);
  transpose256<<<dim3(64), dim3(256), 0, stream>>>(outw, woT);
  pack_mask<<<dim3(B_ * Q_), dim3(256), 0, stream>>>(vidmask, mb);
  qproj<<<dim3(B_ * Q_ / 4), dim3(256), 0, stream>>>(queries, queryembed, wqT, inb, Qb);
  kvproj<<<dim3(B_ * (N_ / 64)), dim3(512), 0, stream>>>(vidfeat, posembed, wkv, inb, Kb, Vb);
  attn<<<dim3(B_ * H_ * NC_), dim3(512), 0, stream>>>(Qb, Kb, Vb, mb, ctxp, lsump);
  epilogue<<<dim3(B_ * Q_), dim3(256), 0, stream>>>(ctxp, lsump, queries, woT, outb, gamma, beta, out);
}